// Round 11
// baseline (807.044 us; speedup 1.0000x reference)
//
#include <hip/hip_runtime.h>

// ---------------------------------------------------------------------------
// TemporalAttnLayer: B=256, T=64, M=256, H=256
//
// Round-11 = Round-10 (fp8 weight stream, wave specialization) with ZERO
// in-loop __syncthreads: full flag-based dataflow pipeline.
//   flagS (dsp ready) -> {gates || x1} -> flagG/flagX -> scores -> flagL
//     -> softmax (wave 8) -> flagY -> LSTM (waves 8-11) -> flagS
// All flags are monotone LDS counters with workgroup-scope acq/rel (r8's
// proven pattern); s_sleep(1) bounds spin issue-pollution. Gate/x1 waves
// prefetch their first weight loads BEFORE the flagS spin (weights are
// step-invariant -> legal), hiding L2 latency under the sync.
// WAR/RAW audit: every buffer overwrite at step t+1 is transitively ordered
// behind its step-t readers via the flag chain (see comments at each post).
// ---------------------------------------------------------------------------

#define Bx 256
#define Tx 64
#define Mx 256
#define Hx 256
#define NT 1024
#define XS 20     // swizzle chunk stride (floats) for xq/vd

typedef unsigned int  uint;
typedef unsigned short ushort;
typedef _Float16 h2  __attribute__((ext_vector_type(2)));
typedef float    f2v __attribute__((ext_vector_type(2)));

__device__ __forceinline__ float4 ld4(const float* p) { return *(const float4*)p; }
__device__ __forceinline__ float h2f(ushort s) {
  union { ushort s; _Float16 h; } c; c.s = s; return (float)c.h;
}
__device__ __forceinline__ ushort f2h(float f) {
  union { _Float16 h; ushort s; } c; c.h = (_Float16)f; return c.s;
}
__device__ __forceinline__ uint pk2(float a, float b) {
  return (uint)f2h(a) | ((uint)f2h(b) << 16);
}
__device__ __forceinline__ float tanh_fast(float x) {
  float e2 = __expf(2.0f * x);
  return 1.0f - 2.0f / (e2 + 1.0f);
}
__device__ __forceinline__ float sigm(float x) {
  return 1.0f / (1.0f + __expf(-x));
}
__device__ __forceinline__ float wave_sum(float v) {
  #pragma unroll
  for (int o = 1; o < 64; o <<= 1) v += __shfl_xor(v, o, 64);
  return v;
}
__device__ __forceinline__ int xsw(int m) { return (m >> 4) * XS + (m & 15); }

// flag helpers: monotone counters in LDS, workgroup scope
__device__ __forceinline__ void fpost(unsigned* f) {
  __threadfence_block();
  if ((threadIdx.x & 63) == 0)
    __hip_atomic_fetch_add(f, 1u, __ATOMIC_RELEASE, __HIP_MEMORY_SCOPE_WORKGROUP);
}
__device__ __forceinline__ void fwait(unsigned* f, unsigned tgt) {
  while (__hip_atomic_load(f, __ATOMIC_ACQUIRE, __HIP_MEMORY_SCOPE_WORKGROUP) < tgt)
    __builtin_amdgcn_s_sleep(1);
}

#if defined(__has_builtin)
#if __has_builtin(__builtin_amdgcn_fdot2)
#define HAVE_FDOT2 1
#endif
#if __has_builtin(__builtin_amdgcn_cvt_pk_f32_fp8) && __has_builtin(__builtin_amdgcn_cvt_pk_fp8_f32)
#define HAVE_FP8 1
#endif
#endif

__device__ __forceinline__ float dot2u(uint w, uint a, float acc) {
#ifdef HAVE_FDOT2
  h2 W = __builtin_bit_cast(h2, w);
  h2 A = __builtin_bit_cast(h2, a);
  return __builtin_amdgcn_fdot2(W, A, acc, false);
#else
  return acc + h2f((ushort)w) * h2f((ushort)a)
             + h2f((ushort)(w >> 16)) * h2f((ushort)(a >> 16));
#endif
}

// ---- fp8 e4m3fn encode/decode (HW path + software fallback) ----
__device__ __forceinline__ uint sw8(float f) {
  union { float f; uint u; } c; c.f = f;
  uint s = (c.u >> 31) << 7;
  float a = fabsf(f);
  if (!(a >= 0.0009765625f)) return s;
  if (a >= 448.f) return s | 0x7e;
  int e = (int)((c.u >> 23) & 0xff) - 127;
  if (e < -6) { int q = (int)(a * 512.f + 0.5f); return s | (uint)q; }
  uint m = ((c.u & 0x7fffff) + 0x80000) >> 20;
  if (m == 8) { m = 0; ++e; }
  if (e > 8) return s | 0x7e;
  return s | ((uint)(e + 7) << 3) | m;
}
__device__ __forceinline__ float sw8d(uint b) {
  uint s = b >> 7, e = (b >> 3) & 0xf, m = b & 7;
  float v;
  if (e) { union { uint u; float f; } c; c.u = ((e + 120u) << 23) | (m << 20); v = c.f; }
  else v = (float)m * 0.001953125f;
  return s ? -v : v;
}
__device__ __forceinline__ uint pk_fp8x4(float w0, float w1, float w2, float w3) {
#ifdef HAVE_FP8
  int u = 0;
  u = __builtin_amdgcn_cvt_pk_fp8_f32(w0, w1, u, false);
  u = __builtin_amdgcn_cvt_pk_fp8_f32(w2, w3, u, true);
  return (uint)u;
#else
  return sw8(w0) | (sw8(w1) << 8) | (sw8(w2) << 16) | (sw8(w3) << 24);
#endif
}
template <bool HI>
__device__ __forceinline__ f2v dec2(uint w) {
#ifdef HAVE_FP8
  return __builtin_amdgcn_cvt_pk_f32_fp8((int)w, HI);
#else
  uint b0 = HI ? ((w >> 16) & 0xffu) : (w & 0xffu);
  uint b1 = HI ? (w >> 24) : ((w >> 8) & 0xffu);
  return f2v{sw8d(b0), sw8d(b1)};
#endif
}
__device__ __forceinline__ f2v dotq(uint w, float4 a, f2v acc) {
  acc += dec2<false>(w) * f2v{a.x, a.y};
  acc += dec2<true>(w)  * f2v{a.z, a.w};
  return acc;
}

// ---------------------------------------------------------------------------
// Pack kernel (unchanged from r10).
// ---------------------------------------------------------------------------
__global__ __launch_bounds__(256)
void pack_weights(const float* __restrict__ W_d,
                  const float* __restrict__ W_hh,
                  const float* __restrict__ U_d,
                  const float* __restrict__ W_y,
                  uint4* __restrict__ Whh8q,
                  uint4* __restrict__ Wd8q,
                  uint4* __restrict__ Ud8,
                  float* __restrict__ Wyt) {
  const int blk = blockIdx.x, tid = threadIdx.x;
  if (blk < 16) {                        // Whh8q
    const int k16 = blk;
    #pragma unroll
    for (int q = 0; q < 4; ++q) {
      const int j = tid + 256 * q;
      const float* wr = W_hh + (size_t)j * 256 + 16 * k16;
      float4 a = ld4(wr), b = ld4(wr + 4), c = ld4(wr + 8), d = ld4(wr + 12);
      uint4 u;
      u.x = pk_fp8x4(16.f * a.x, 16.f * a.y, 16.f * a.z, 16.f * a.w);
      u.y = pk_fp8x4(16.f * b.x, 16.f * b.y, 16.f * b.z, 16.f * b.w);
      u.z = pk_fp8x4(16.f * c.x, 16.f * c.y, 16.f * c.z, 16.f * c.w);
      u.w = pk_fp8x4(16.f * d.x, 16.f * d.y, 16.f * d.z, 16.f * d.w);
      Whh8q[k16 * 1024 + j] = u;
    }
  } else if (blk < 48) {                 // Wd8q
    const int k16 = blk - 16;
    const float* wr = W_d + (size_t)tid * 512 + 16 * k16;
    float4 a = ld4(wr), b = ld4(wr + 4), c = ld4(wr + 8), d = ld4(wr + 12);
    uint4 u;
    u.x = pk_fp8x4(16.f * a.x, 16.f * a.y, 16.f * a.z, 16.f * a.w);
    u.y = pk_fp8x4(16.f * b.x, 16.f * b.y, 16.f * b.z, 16.f * b.w);
    u.z = pk_fp8x4(16.f * c.x, 16.f * c.y, 16.f * c.z, 16.f * c.w);
    u.w = pk_fp8x4(16.f * d.x, 16.f * d.y, 16.f * d.z, 16.f * d.w);
    Wd8q[k16 * 256 + tid] = u;
  } else if (blk < 80) {                 // Ud8 (f16, one-time Y1 build)
    const int m8 = blk - 48;
    float4 a = ld4(U_d + (size_t)tid * 256 + 8 * m8);
    float4 b = ld4(U_d + (size_t)tid * 256 + 8 * m8 + 4);
    Ud8[m8 * 256 + tid] = uint4{pk2(a.x, a.y), pk2(a.z, a.w),
                                pk2(b.x, b.y), pk2(b.z, b.w)};
  } else {                               // Wyt transpose
    const int k0 = (blk - 80) * 4;
    float4 w = ld4(W_y + (size_t)tid * 512 + k0);
    Wyt[(k0 + 0) * 256 + tid] = w.x;
    Wyt[(k0 + 1) * 256 + tid] = w.y;
    Wyt[(k0 + 2) * 256 + tid] = w.z;
    Wyt[(k0 + 3) * 256 + tid] = w.w;
  }
}

// ---------------------------------------------------------------------------
// Main kernel: one 1024-thread wg per batch element, fully independent.
// Waves 0-7 gates; waves 8-15 x1->scores; wave 8 softmax; waves 8-11 LSTM.
// ---------------------------------------------------------------------------
__global__ __launch_bounds__(NT, 4)
void fused(const float* __restrict__ enc,      // (T,B,M)
           const float* __restrict__ yv,       // (B,T,1)
           const float* __restrict__ b_Wd,     // (M)
           const float* __restrict__ v_d,      // (1,M)
           const float* __restrict__ w_tilda,  // (1,M+1)
           const float* __restrict__ b_wt,     // (1)
           const float* __restrict__ W_ih,     // (4H,1)
           const float* __restrict__ b_ih,     // (4H)
           const float* __restrict__ b_hh,     // (4H)
           const float* __restrict__ b_Wy,     // (H)
           const float* __restrict__ v_y,      // (1,H)
           const float* __restrict__ b_vy,     // (1)
           const uint4* __restrict__ Whh8q,
           const uint4* __restrict__ Wd8q,
           const uint4* __restrict__ Ud8,
           const float* __restrict__ Wyt,
           ushort* __restrict__ Y1,            // (B,T,M) f16 scratch
           float* __restrict__ out)            // (B,1)
{
  __shared__ __align__(16) float dsp_s[2 * Hx];     // [d|sp] f32
  __shared__ __align__(16) float xq_s[2 * 16 * XS]; // x1 K-half partials, swz
  __shared__ __align__(16) float vd_s[16 * XS];     // v_d swizzled
  __shared__ float gates_s[1024];                   // gates; epilogue partials
  __shared__ float dcfin_s[2 * Hx];                 // [d|c] fp32 (epilogue)
  __shared__ float l_s[Tx];
  __shared__ uint  beta2_s[Tx / 2];                 // beta packed f16 pairs
  __shared__ float e_s[Tx];                         // E_t
  __shared__ float red_s[4];
  __shared__ float ytil_s;
  __shared__ unsigned flagG, flagX, flagL, flagY, flagS;

  const int b   = blockIdx.x;
  const int tid = threadIdx.x;     // 0..1023
  const int h   = tid & 255;
  const int p   = tid >> 8;        // 0..3
  const size_t BM = (size_t)Bx * Mx;

  // ---- stage 0: params, state, flags ----
  if (tid < 256) vd_s[xsw(tid)] = v_d[tid];
  if (tid < 512) dsp_s[tid] = 0.0f;
  if (tid == 0) { flagG = 0u; flagX = 0u; flagL = 0u; flagY = 0u; flagS = 0u; }

  float bj0 = 0.f, bj1 = 0.f;                  // gate waves
  if (tid < 512) { bj0 = b_ih[tid] + b_hh[tid]; bj1 = b_ih[tid + 512] + b_hh[tid + 512]; }
  float bWd_r = 0.f;                           // x1 half-0 threads
  if (tid >= 512 && tid < 768) bWd_r = b_Wd[tid - 512];
  float wih0 = 0.f, wih1 = 0.f, wih2 = 0.f, wih3 = 0.f;  // LSTM threads
  if (tid >= 512 && tid < 768) {
    const int hh = tid - 512;
    wih0 = W_ih[hh]; wih1 = W_ih[hh + 256]; wih2 = W_ih[hh + 512]; wih3 = W_ih[hh + 768];
  }
  float yv_r = 0.f;                            // softmax wave
  if (tid >= 512 && tid < 576) yv_r = yv[b * Tx + (tid - 512)];
  const float wty = w_tilda[Mx];
  const float bwt = b_wt[0];

  // ---- stage 0b: E_t = sum_m w~_m enc[t][b][m] (one-time) ----
  if (tid < Tx) {
    const float* er = enc + (size_t)tid * BM + (size_t)b * Mx;
    float acc = 0.0f;
    for (int m = 0; m < Mx; m += 4) {
      float4 e4 = ld4(er + m);
      float4 w4 = ld4(w_tilda + m);
      acc += e4.x * w4.x + e4.y * w4.y + e4.z * w4.z + e4.w * w4.w;
    }
    e_s[tid] = acc;
  }

  // ---- stage 1: Y1[b] = enc[b] @ U_d^T (packed-fp32 FMA, f16 weights) ----
  {
    const int n = h;
    const float* eb = enc + (size_t)b * Mx;
    for (int tb = p * 16; tb < p * 16 + 16; tb += 8) {
      f2v acc2[8];
      #pragma unroll
      for (int j = 0; j < 8; ++j) acc2[j] = f2v{0.f, 0.f};
      #pragma unroll 2
      for (int m8 = 0; m8 < 32; ++m8) {
        uint4 u = Ud8[m8 * 256 + n];
        f2v w01 = f2v{h2f((ushort)u.x), h2f((ushort)(u.x >> 16))};
        f2v w23 = f2v{h2f((ushort)u.y), h2f((ushort)(u.y >> 16))};
        f2v w45 = f2v{h2f((ushort)u.z), h2f((ushort)(u.z >> 16))};
        f2v w67 = f2v{h2f((ushort)u.w), h2f((ushort)(u.w >> 16))};
        #pragma unroll
        for (int j = 0; j < 8; ++j) {
          const float* ep = eb + (size_t)(tb + j) * BM + 8 * m8;
          float4 ea = ld4(ep), eb4 = ld4(ep + 4);
          acc2[j] += f2v{ea.x, ea.y} * w01;
          acc2[j] += f2v{ea.z, ea.w} * w23;
          acc2[j] += f2v{eb4.x, eb4.y} * w45;
          acc2[j] += f2v{eb4.z, eb4.w} * w67;
        }
      }
      #pragma unroll
      for (int j = 0; j < 8; ++j)
        Y1[((size_t)b * Tx + tb + j) * Mx + n] = f2h(acc2[j].x + acc2[j].y);
    }
  }
  __syncthreads();  // S1: dsp_s, vd_s, e_s, flags, Y1 ready

  float sp_reg = 0.0f;   // LSTM threads (tid 512..767)

  for (int t = 0; t < Tx; ++t) {
    if (tid < 512) {
      // ===== GATE WAVES ===== (outputs j=tid, tid+512)
      const uint4* wp = Whh8q + tid;
      uint4 wa0 = wp[0], wb0 = wp[512];        // prefetch under the spin
      fwait(&flagS, 4u * (unsigned)t);         // dsp_s(t-1) ready
      f2v ga = f2v{0.f, 0.f}, gb = f2v{0.f, 0.f};
      {
        const float4* ap = (const float4*)dsp_s;
        float4 a0 = ap[0], a1 = ap[1], a2 = ap[2], a3 = ap[3];
        ga = dotq(wa0.x, a0, ga); ga = dotq(wa0.y, a1, ga);
        ga = dotq(wa0.z, a2, ga); ga = dotq(wa0.w, a3, ga);
        gb = dotq(wb0.x, a0, gb); gb = dotq(wb0.y, a1, gb);
        gb = dotq(wb0.z, a2, gb); gb = dotq(wb0.w, a3, gb);
      }
      #pragma unroll 3
      for (int c = 1; c < 16; ++c) {
        uint4 wa = wp[c * 1024];
        uint4 wb = wp[c * 1024 + 512];
        const float4* ap = (const float4*)dsp_s + 4 * c;
        float4 a0 = ap[0], a1 = ap[1], a2 = ap[2], a3 = ap[3];
        ga = dotq(wa.x, a0, ga); ga = dotq(wa.y, a1, ga);
        ga = dotq(wa.z, a2, ga); ga = dotq(wa.w, a3, ga);
        gb = dotq(wb.x, a0, gb); gb = dotq(wb.y, a1, gb);
        gb = dotq(wb.z, a2, gb); gb = dotq(wb.w, a3, gb);
      }
      gates_s[tid]       = (ga.x + ga.y) * 0.0625f + bj0;
      gates_s[tid + 512] = (gb.x + gb.y) * 0.0625f + bj1;
      fpost(&flagG);   // gates(t) written; also marks our dsp_s reads done
    } else {
      // ===== SCORE WAVES =====
      const int idx = tid - 512;               // 0..511
      const int m = idx & 255, q = idx >> 8;   // x1: output m, K-half q
      {
        const uint4* xp = Wd8q + m + (q * 16) * 256;
        uint4 u0 = xp[0];                      // prefetch under the spin
        fwait(&flagS, 4u * (unsigned)t);       // dsp_s(t-1) ready
        f2v xa2 = f2v{0.f, 0.f};
        {
          const float4* ap = (const float4*)dsp_s + 64 * q;
          xa2 = dotq(u0.x, ap[0], xa2); xa2 = dotq(u0.y, ap[1], xa2);
          xa2 = dotq(u0.z, ap[2], xa2); xa2 = dotq(u0.w, ap[3], xa2);
        }
        #pragma unroll 3
        for (int i = 1; i < 16; ++i) {
          uint4 u = xp[i * 256];
          const float4* ap = (const float4*)dsp_s + 64 * q + 4 * i;
          xa2 = dotq(u.x, ap[0], xa2); xa2 = dotq(u.y, ap[1], xa2);
          xa2 = dotq(u.z, ap[2], xa2); xa2 = dotq(u.w, ap[3], xa2);
        }
        xq_s[q * (16 * XS) + xsw(m)] = (xa2.x + xa2.y) * 0.0625f
                                     + (q == 0 ? bWd_r : 0.0f);
      }
      fpost(&flagX);   // xq(t) written; our dsp_s reads done
      fwait(&flagX, 8u * (unsigned)(t + 1));

      // scores: 8 lanes/query, lane covers 32 m's
      {
        const int tq = idx >> 3, lq = idx & 7;
        const ushort* y1r = Y1 + ((size_t)b * Tx + tq) * Mx + lq * 32;
        float ps = 0.0f;
        #pragma unroll
        for (int g = 0; g < 8; ++g) {
          const int c   = 2 * lq + (g >> 2);
          const int off = c * XS + 4 * (g & 3);
          float4 xa0 = *(const float4*)(xq_s + off);
          float4 xa1 = *(const float4*)(xq_s + 16 * XS + off);
          float4 vv  = *(const float4*)(vd_s + off);
          uint2 yy = *(const uint2*)(y1r + 4 * g);
          ps += tanh_fast(xa0.x + xa1.x + h2f((ushort)yy.x)) * vv.x
              + tanh_fast(xa0.y + xa1.y + h2f((ushort)(yy.x >> 16))) * vv.y
              + tanh_fast(xa0.z + xa1.z + h2f((ushort)yy.y)) * vv.z
              + tanh_fast(xa0.w + xa1.w + h2f((ushort)(yy.y >> 16))) * vv.w;
        }
        ps += __shfl_xor(ps, 1, 64);
        ps += __shfl_xor(ps, 2, 64);
        ps += __shfl_xor(ps, 4, 64);
        if (lq == 0) l_s[tq] = ps;
      }
      fpost(&flagL);   // l(t) written; our xq reads done

      if (idx < 64) {
        // softmax + beta pack + ytil (wave 8)
        fwait(&flagL, 8u * (unsigned)(t + 1));
        float v = l_s[idx];
        float mx = v;
        #pragma unroll
        for (int o = 1; o < 64; o <<= 1) mx = fmaxf(mx, __shfl_xor(mx, o, 64));
        float e = __expf(v - mx);
        float sm = e;
        #pragma unroll
        for (int o = 1; o < 64; o <<= 1) sm += __shfl_xor(sm, o, 64);
        float beta = e / sm;
        float bnext = __shfl_xor(beta, 1, 64);
        if ((idx & 1) == 0) beta2_s[idx >> 1] = pk2(beta, bnext);
        float term = beta * e_s[idx] + ((idx == t) ? (wty * yv_r + bwt) : 0.0f);
        float yt = wave_sum(term);
        if (idx == 0) ytil_s = yt;
        fpost(&flagY);  // ytil(t) + beta2(t) ready; l_s reads done
      }
      if (idx < 256) {
        // ===== LSTM (waves 8-11) =====
        fwait(&flagY, (unsigned)(t + 1));
        fwait(&flagG, 8u * (unsigned)(t + 1));  // gates(t) written, all gate
                                                // waves' dsp reads done
        const int hh = idx;
        const float ytil = ytil_s;
        float fi = sigm(gates_s[hh]       + ytil * wih0);
        float ff = sigm(gates_s[256 + hh] + ytil * wih1);
        float fg = tanh_fast(gates_s[512 + hh] + ytil * wih2);
        float fo = sigm(gates_s[768 + hh] + ytil * wih3);
        float spn = ff * sp_reg + fi * fg;
        float dn  = fo * tanh_fast(spn);
        sp_reg = spn;
        dsp_s[hh]       = dn;
        dsp_s[256 + hh] = spn;
        if (t == Tx - 1) dcfin_s[hh] = dn;
        fpost(&flagS);  // dsp(t) ready; gates_s/ytil reads done
      }
    }
  }

  __syncthreads();  // loop complete: beta2_s(63), dcfin_s[d] final

  // ===== one-time context c (beta of t=63): threads >=512, 2 lanes per m ====
  if (tid >= 512) {
    const int idx = tid - 512;
    const int m = idx >> 1, q = idx & 1;
    float acc = 0.0f;
    #pragma unroll 4
    for (int j = 0; j < 32; ++j) {
      const int tt = q * 32 + j;
      uint bp = beta2_s[tt >> 1];
      float bb = (tt & 1) ? h2f((ushort)(bp >> 16)) : h2f((ushort)bp);
      acc += bb * enc[(size_t)tt * BM + (size_t)b * Mx + m];
    }
    acc += __shfl_xor(acc, 1, 64);
    if (q == 0) dcfin_s[256 + m] = acc;
  }
  __syncthreads();

  // ===== Epilogue: out[b] = v_y . (W_y @ [d|c] + b_Wy) + b_vy =====
  {
    float a = 0.0f;
    const float* wy = Wyt + h;
    for (int k = 128 * p; k < 128 * p + 128; ++k)
      a += wy[(size_t)k * 256] * dcfin_s[k];
    gates_s[p * 256 + h] = a;     // gates_s reused as epilogue partials
  }
  __syncthreads();
  if (tid < 256) {
    float aa = gates_s[h] + gates_s[256 + h] + gates_s[512 + h] + gates_s[768 + h]
             + b_Wy[h];
    float po = aa * v_y[h];
    po = wave_sum(po);
    if ((tid & 63) == 0) red_s[tid >> 6] = po;
  }
  __syncthreads();
  if (tid == 0) out[b] = red_s[0] + red_s[1] + red_s[2] + red_s[3] + b_vy[0];
}

extern "C" void kernel_launch(void* const* d_in, const int* in_sizes, int n_in,
                              void* d_out, int out_size, void* d_ws, size_t ws_size,
                              hipStream_t stream) {
  const float* enc     = (const float*)d_in[0];
  const float* yv      = (const float*)d_in[1];
  const float* W_d     = (const float*)d_in[2];
  const float* b_Wd    = (const float*)d_in[3];
  const float* U_d     = (const float*)d_in[4];
  const float* v_d     = (const float*)d_in[5];
  const float* w_tilda = (const float*)d_in[6];
  const float* b_wt    = (const float*)d_in[7];
  const float* W_ih    = (const float*)d_in[8];
  const float* W_hh    = (const float*)d_in[9];
  const float* b_ih    = (const float*)d_in[10];
  const float* b_hh    = (const float*)d_in[11];
  const float* W_y     = (const float*)d_in[12];
  const float* b_Wy    = (const float*)d_in[13];
  const float* v_y     = (const float*)d_in[14];
  const float* b_vy    = (const float*)d_in[15];
  float* outp = (float*)d_out;

  char* ws = (char*)d_ws;
  uint4* Whh8q = (uint4*)ws;                               // 256 KB
  uint4* Wd8q  = (uint4*)(ws + (256 << 10));               // 128 KB
  uint4* Ud8   = (uint4*)(ws + (384 << 10));               // 128 KB
  float* Wyt   = (float*)(ws + (512 << 10));               // 512 KB
  ushort* Y1   = (ushort*)(ws + (1024 << 10));             // 8 MB

  hipLaunchKernelGGL(pack_weights, dim3(208), dim3(256), 0, stream,
                     W_d, W_hh, U_d, W_y, Whh8q, Wd8q, Ud8, Wyt);
  hipLaunchKernelGGL(fused, dim3(Bx), dim3(NT), 0, stream,
                     enc, yv, b_Wd, v_d, w_tilda, b_wt, W_ih, b_ih, b_hh,
                     b_Wy, v_y, b_vy, Whh8q, Wd8q, Ud8, Wyt, Y1, outp);
}

// Round 12
// 701.784 us; speedup vs baseline: 1.1500x; 1.1500x over previous
//
#include <hip/hip_runtime.h>

// ---------------------------------------------------------------------------
// TemporalAttnLayer: B=256, T=64, M=256, H=256
//
// Round-12 = Round-10 (best: 722 us; fp8 stream, wave specialization,
// 2 barriers + 2 subset flags per step) + two latency/byte levers:
//  - W_d (128 KB fp8) pinned in DYNAMIC LDS (one-time copy): per-step L2
//    stream 384 -> 256 KB/CU, and x1 (first stage of the serial chain)
//    reads LDS instead of contended L2. Total LDS ~141 KB -> true 1 block/CU
//    (also unlocks the >64-VGPR allocator budget per r5/r6 forensics).
//  - Y1 score rows prefetched into registers BEFORE the flagX wait (loads
//    independent of x1 -> hidden under the spin instead of after it).
// r11 lesson: full flag-chain pipeline REGRESSED (807 vs 722) - spins steal
// issue from streaming waves; the two coarse barriers stay.
// ---------------------------------------------------------------------------

#define Bx 256
#define Tx 64
#define Mx 256
#define Hx 256
#define NT 1024
#define XS 20     // swizzle chunk stride (floats) for xq/vd

typedef unsigned int  uint;
typedef unsigned short ushort;
typedef _Float16 h2  __attribute__((ext_vector_type(2)));
typedef float    f2v __attribute__((ext_vector_type(2)));

__device__ __forceinline__ float4 ld4(const float* p) { return *(const float4*)p; }
__device__ __forceinline__ float h2f(ushort s) {
  union { ushort s; _Float16 h; } c; c.s = s; return (float)c.h;
}
__device__ __forceinline__ ushort f2h(float f) {
  union { _Float16 h; ushort s; } c; c.h = (_Float16)f; return c.s;
}
__device__ __forceinline__ uint pk2(float a, float b) {
  return (uint)f2h(a) | ((uint)f2h(b) << 16);
}
__device__ __forceinline__ float tanh_fast(float x) {
  float e2 = __expf(2.0f * x);
  return 1.0f - 2.0f / (e2 + 1.0f);
}
__device__ __forceinline__ float sigm(float x) {
  return 1.0f / (1.0f + __expf(-x));
}
__device__ __forceinline__ float wave_sum(float v) {
  #pragma unroll
  for (int o = 1; o < 64; o <<= 1) v += __shfl_xor(v, o, 64);
  return v;
}
__device__ __forceinline__ int xsw(int m) { return (m >> 4) * XS + (m & 15); }

#if defined(__has_builtin)
#if __has_builtin(__builtin_amdgcn_fdot2)
#define HAVE_FDOT2 1
#endif
#if __has_builtin(__builtin_amdgcn_cvt_pk_f32_fp8) && __has_builtin(__builtin_amdgcn_cvt_pk_fp8_f32)
#define HAVE_FP8 1
#endif
#endif

__device__ __forceinline__ float dot2u(uint w, uint a, float acc) {
#ifdef HAVE_FDOT2
  h2 W = __builtin_bit_cast(h2, w);
  h2 A = __builtin_bit_cast(h2, a);
  return __builtin_amdgcn_fdot2(W, A, acc, false);
#else
  return acc + h2f((ushort)w) * h2f((ushort)a)
             + h2f((ushort)(w >> 16)) * h2f((ushort)(a >> 16));
#endif
}

// ---- fp8 e4m3fn encode/decode (HW path + software fallback) ----
__device__ __forceinline__ uint sw8(float f) {
  union { float f; uint u; } c; c.f = f;
  uint s = (c.u >> 31) << 7;
  float a = fabsf(f);
  if (!(a >= 0.0009765625f)) return s;
  if (a >= 448.f) return s | 0x7e;
  int e = (int)((c.u >> 23) & 0xff) - 127;
  if (e < -6) { int q = (int)(a * 512.f + 0.5f); return s | (uint)q; }
  uint m = ((c.u & 0x7fffff) + 0x80000) >> 20;
  if (m == 8) { m = 0; ++e; }
  if (e > 8) return s | 0x7e;
  return s | ((uint)(e + 7) << 3) | m;
}
__device__ __forceinline__ float sw8d(uint b) {
  uint s = b >> 7, e = (b >> 3) & 0xf, m = b & 7;
  float v;
  if (e) { union { uint u; float f; } c; c.u = ((e + 120u) << 23) | (m << 20); v = c.f; }
  else v = (float)m * 0.001953125f;
  return s ? -v : v;
}
__device__ __forceinline__ uint pk_fp8x4(float w0, float w1, float w2, float w3) {
#ifdef HAVE_FP8
  int u = 0;
  u = __builtin_amdgcn_cvt_pk_fp8_f32(w0, w1, u, false);
  u = __builtin_amdgcn_cvt_pk_fp8_f32(w2, w3, u, true);
  return (uint)u;
#else
  return sw8(w0) | (sw8(w1) << 8) | (sw8(w2) << 16) | (sw8(w3) << 24);
#endif
}
template <bool HI>
__device__ __forceinline__ f2v dec2(uint w) {
#ifdef HAVE_FP8
  return __builtin_amdgcn_cvt_pk_f32_fp8((int)w, HI);
#else
  uint b0 = HI ? ((w >> 16) & 0xffu) : (w & 0xffu);
  uint b1 = HI ? (w >> 24) : ((w >> 8) & 0xffu);
  return f2v{sw8d(b0), sw8d(b1)};
#endif
}
__device__ __forceinline__ f2v dotq(uint w, float4 a, f2v acc) {
  acc += dec2<false>(w) * f2v{a.x, a.y};
  acc += dec2<true>(w)  * f2v{a.z, a.w};
  return acc;
}

// ---------------------------------------------------------------------------
// Pack kernel (unchanged from r10).
// ---------------------------------------------------------------------------
__global__ __launch_bounds__(256)
void pack_weights(const float* __restrict__ W_d,
                  const float* __restrict__ W_hh,
                  const float* __restrict__ U_d,
                  const float* __restrict__ W_y,
                  uint4* __restrict__ Whh8q,
                  uint4* __restrict__ Wd8q,
                  uint4* __restrict__ Ud8,
                  float* __restrict__ Wyt) {
  const int blk = blockIdx.x, tid = threadIdx.x;
  if (blk < 16) {                        // Whh8q
    const int k16 = blk;
    #pragma unroll
    for (int q = 0; q < 4; ++q) {
      const int j = tid + 256 * q;
      const float* wr = W_hh + (size_t)j * 256 + 16 * k16;
      float4 a = ld4(wr), b = ld4(wr + 4), c = ld4(wr + 8), d = ld4(wr + 12);
      uint4 u;
      u.x = pk_fp8x4(16.f * a.x, 16.f * a.y, 16.f * a.z, 16.f * a.w);
      u.y = pk_fp8x4(16.f * b.x, 16.f * b.y, 16.f * b.z, 16.f * b.w);
      u.z = pk_fp8x4(16.f * c.x, 16.f * c.y, 16.f * c.z, 16.f * c.w);
      u.w = pk_fp8x4(16.f * d.x, 16.f * d.y, 16.f * d.z, 16.f * d.w);
      Whh8q[k16 * 1024 + j] = u;
    }
  } else if (blk < 48) {                 // Wd8q
    const int k16 = blk - 16;
    const float* wr = W_d + (size_t)tid * 512 + 16 * k16;
    float4 a = ld4(wr), b = ld4(wr + 4), c = ld4(wr + 8), d = ld4(wr + 12);
    uint4 u;
    u.x = pk_fp8x4(16.f * a.x, 16.f * a.y, 16.f * a.z, 16.f * a.w);
    u.y = pk_fp8x4(16.f * b.x, 16.f * b.y, 16.f * b.z, 16.f * b.w);
    u.z = pk_fp8x4(16.f * c.x, 16.f * c.y, 16.f * c.z, 16.f * c.w);
    u.w = pk_fp8x4(16.f * d.x, 16.f * d.y, 16.f * d.z, 16.f * d.w);
    Wd8q[k16 * 256 + tid] = u;
  } else if (blk < 80) {                 // Ud8 (f16, one-time Y1 build)
    const int m8 = blk - 48;
    float4 a = ld4(U_d + (size_t)tid * 256 + 8 * m8);
    float4 b = ld4(U_d + (size_t)tid * 256 + 8 * m8 + 4);
    Ud8[m8 * 256 + tid] = uint4{pk2(a.x, a.y), pk2(a.z, a.w),
                                pk2(b.x, b.y), pk2(b.z, b.w)};
  } else {                               // Wyt transpose
    const int k0 = (blk - 80) * 4;
    float4 w = ld4(W_y + (size_t)tid * 512 + k0);
    Wyt[(k0 + 0) * 256 + tid] = w.x;
    Wyt[(k0 + 1) * 256 + tid] = w.y;
    Wyt[(k0 + 2) * 256 + tid] = w.z;
    Wyt[(k0 + 3) * 256 + tid] = w.w;
  }
}

// ---------------------------------------------------------------------------
// Main kernel: one 1024-thread wg per batch element, fully independent.
// Waves 0-7 gates; waves 8-15 x1 (from LDS) -> scores; wave 8 softmax;
// waves 8-11 LSTM.  W_d lives in 128 KB dynamic LDS (one-time copy).
// ---------------------------------------------------------------------------
__global__ __launch_bounds__(NT, 1)
void fused(const float* __restrict__ enc,      // (T,B,M)
           const float* __restrict__ yv,       // (B,T,1)
           const float* __restrict__ b_Wd,     // (M)
           const float* __restrict__ v_d,      // (1,M)
           const float* __restrict__ w_tilda,  // (1,M+1)
           const float* __restrict__ b_wt,     // (1)
           const float* __restrict__ W_ih,     // (4H,1)
           const float* __restrict__ b_ih,     // (4H)
           const float* __restrict__ b_hh,     // (4H)
           const float* __restrict__ b_Wy,     // (H)
           const float* __restrict__ v_y,      // (1,H)
           const float* __restrict__ b_vy,     // (1)
           const uint4* __restrict__ Whh8q,
           const uint4* __restrict__ Wd8q,
           const uint4* __restrict__ Ud8,
           const float* __restrict__ Wyt,
           ushort* __restrict__ Y1,            // (B,T,M) f16 scratch
           float* __restrict__ out)            // (B,1)
{
  extern __shared__ __align__(16) uint4 wdl[];      // 8192 uint4 = 128 KB W_d
  __shared__ __align__(16) float dsp_s[2 * Hx];     // [d|sp] f32
  __shared__ __align__(16) float xq_s[2 * 16 * XS]; // x1 K-half partials, swz
  __shared__ __align__(16) float vd_s[16 * XS];     // v_d swizzled
  __shared__ float gates_s[1024];                   // gates; epilogue partials
  __shared__ float dcfin_s[2 * Hx];                 // [d|c] fp32 (epilogue)
  __shared__ float l_s[Tx];
  __shared__ uint  beta2_s[Tx / 2];                 // beta packed f16 pairs
  __shared__ float e_s[Tx];                         // E_t
  __shared__ float red_s[4];
  __shared__ float ytil_s;
  __shared__ unsigned flagX, flagL;

  const int b   = blockIdx.x;
  const int tid = threadIdx.x;     // 0..1023
  const int h   = tid & 255;
  const int p   = tid >> 8;        // 0..3
  const size_t BM = (size_t)Bx * Mx;

  // ---- stage 0: W_d -> LDS (one-time), params, state, flags ----
  #pragma unroll
  for (int i = 0; i < 8; ++i) wdl[i * NT + tid] = Wd8q[i * NT + tid];
  if (tid < 256) vd_s[xsw(tid)] = v_d[tid];
  if (tid < 512) dsp_s[tid] = 0.0f;
  if (tid == 0) { flagX = 0u; flagL = 0u; }

  float bj0 = 0.f, bj1 = 0.f;                  // gate waves
  if (tid < 512) { bj0 = b_ih[tid] + b_hh[tid]; bj1 = b_ih[tid + 512] + b_hh[tid + 512]; }
  float bWd_r = 0.f;                           // x1 half-0 threads
  if (tid >= 512 && tid < 768) bWd_r = b_Wd[tid - 512];
  float wih0 = 0.f, wih1 = 0.f, wih2 = 0.f, wih3 = 0.f;  // LSTM threads
  if (tid >= 512 && tid < 768) {
    const int hh = tid - 512;
    wih0 = W_ih[hh]; wih1 = W_ih[hh + 256]; wih2 = W_ih[hh + 512]; wih3 = W_ih[hh + 768];
  }
  float yv_r = 0.f;                            // softmax wave
  if (tid >= 512 && tid < 576) yv_r = yv[b * Tx + (tid - 512)];
  const float wty = w_tilda[Mx];
  const float bwt = b_wt[0];

  // ---- stage 0b: E_t = sum_m w~_m enc[t][b][m] (one-time) ----
  if (tid < Tx) {
    const float* er = enc + (size_t)tid * BM + (size_t)b * Mx;
    float acc = 0.0f;
    for (int m = 0; m < Mx; m += 4) {
      float4 e4 = ld4(er + m);
      float4 w4 = ld4(w_tilda + m);
      acc += e4.x * w4.x + e4.y * w4.y + e4.z * w4.z + e4.w * w4.w;
    }
    e_s[tid] = acc;
  }

  // ---- stage 1: Y1[b] = enc[b] @ U_d^T (packed-fp32 FMA, f16 weights) ----
  {
    const int n = h;
    const float* eb = enc + (size_t)b * Mx;
    for (int tb = p * 16; tb < p * 16 + 16; tb += 8) {
      f2v acc2[8];
      #pragma unroll
      for (int j = 0; j < 8; ++j) acc2[j] = f2v{0.f, 0.f};
      #pragma unroll 2
      for (int m8 = 0; m8 < 32; ++m8) {
        uint4 u = Ud8[m8 * 256 + n];
        f2v w01 = f2v{h2f((ushort)u.x), h2f((ushort)(u.x >> 16))};
        f2v w23 = f2v{h2f((ushort)u.y), h2f((ushort)(u.y >> 16))};
        f2v w45 = f2v{h2f((ushort)u.z), h2f((ushort)(u.z >> 16))};
        f2v w67 = f2v{h2f((ushort)u.w), h2f((ushort)(u.w >> 16))};
        #pragma unroll
        for (int j = 0; j < 8; ++j) {
          const float* ep = eb + (size_t)(tb + j) * BM + 8 * m8;
          float4 ea = ld4(ep), eb4 = ld4(ep + 4);
          acc2[j] += f2v{ea.x, ea.y} * w01;
          acc2[j] += f2v{ea.z, ea.w} * w23;
          acc2[j] += f2v{eb4.x, eb4.y} * w45;
          acc2[j] += f2v{eb4.z, eb4.w} * w67;
        }
      }
      #pragma unroll
      for (int j = 0; j < 8; ++j)
        Y1[((size_t)b * Tx + tb + j) * Mx + n] = f2h(acc2[j].x + acc2[j].y);
    }
  }
  __syncthreads();  // S1: wdl, dsp_s, vd_s, e_s, flags, Y1 ready

  float sp_reg = 0.0f;   // LSTM threads (tid 512..767)

  for (int t = 0; t < Tx; ++t) {
    if (tid < 512) {
      // ===== GATE WAVES: outputs j=tid, tid+512; fp8 stream 256 KB =====
      f2v ga = f2v{0.f, 0.f}, gb = f2v{0.f, 0.f};
      const uint4* wp = Whh8q + tid;
      #pragma unroll 2
      for (int c = 0; c < 16; ++c) {
        uint4 wa = wp[c * 1024];
        uint4 wb = wp[c * 1024 + 512];
        const float4* ap = (const float4*)dsp_s + 4 * c;   // broadcast
        float4 a0 = ap[0], a1 = ap[1], a2 = ap[2], a3 = ap[3];
        ga = dotq(wa.x, a0, ga); ga = dotq(wa.y, a1, ga);
        ga = dotq(wa.z, a2, ga); ga = dotq(wa.w, a3, ga);
        gb = dotq(wb.x, a0, gb); gb = dotq(wb.y, a1, gb);
        gb = dotq(wb.z, a2, gb); gb = dotq(wb.w, a3, gb);
      }
      gates_s[tid]       = (ga.x + ga.y) * 0.0625f + bj0;
      gates_s[tid + 512] = (gb.x + gb.y) * 0.0625f + bj1;
    } else {
      // ===== SCORE WAVES =====
      const int idx = tid - 512;               // 0..511
      const int m = idx & 255, q = idx >> 8;   // x1: output m, K-half q
      const int tq = idx >> 3, lq = idx & 7;
      // Y1 prefetch (independent of x1) - hidden under x1 + the flagX spin
      const ushort* y1r = Y1 + ((size_t)b * Tx + tq) * Mx + lq * 32;
      uint4 yq0 = *(const uint4*)(y1r);
      uint4 yq1 = *(const uint4*)(y1r + 8);
      uint4 yq2 = *(const uint4*)(y1r + 16);
      uint4 yq3 = *(const uint4*)(y1r + 24);
      {
        f2v xa2 = f2v{0.f, 0.f};
        const uint4* xp = wdl + m + (q * 16) * 256;        // LDS W_d
        #pragma unroll 4
        for (int i = 0; i < 16; ++i) {
          uint4 u = xp[i * 256];
          const float4* ap = (const float4*)dsp_s + 64 * q + 4 * i;  // bcast
          float4 a0 = ap[0], a1 = ap[1], a2 = ap[2], a3 = ap[3];
          xa2 = dotq(u.x, a0, xa2); xa2 = dotq(u.y, a1, xa2);
          xa2 = dotq(u.z, a2, xa2); xa2 = dotq(u.w, a3, xa2);
        }
        xq_s[q * (16 * XS) + xsw(m)] = (xa2.x + xa2.y) * 0.0625f
                                     + (q == 0 ? bWd_r : 0.0f);
      }
      __threadfence_block();
      if ((threadIdx.x & 63) == 0)
        __hip_atomic_fetch_add(&flagX, 1u, __ATOMIC_RELEASE, __HIP_MEMORY_SCOPE_WORKGROUP);
      const unsigned tgtX = 8u * (unsigned)(t + 1);
      while (__hip_atomic_load(&flagX, __ATOMIC_ACQUIRE, __HIP_MEMORY_SCOPE_WORKGROUP) < tgtX) {}

      // scores: 8 lanes/query, lane covers 32 m's (Y1 already in regs)
      {
        float ps = 0.0f;
        uint yy[8] = {yq0.x, yq0.y, yq0.z, yq0.w, yq1.x, yq1.y, yq1.z, yq1.w};
        uint zz[8] = {yq2.x, yq2.y, yq2.z, yq2.w, yq3.x, yq3.y, yq3.z, yq3.w};
        #pragma unroll
        for (int g = 0; g < 8; ++g) {
          const int c   = 2 * lq + (g >> 2);
          const int off = c * XS + 4 * (g & 3);
          float4 xa0 = *(const float4*)(xq_s + off);
          float4 xa1 = *(const float4*)(xq_s + 16 * XS + off);
          float4 vv  = *(const float4*)(vd_s + off);
          uint ya = (g < 4) ? yy[2 * g] : zz[2 * (g - 4)];
          uint yb = (g < 4) ? yy[2 * g + 1] : zz[2 * (g - 4) + 1];
          ps += tanh_fast(xa0.x + xa1.x + h2f((ushort)ya)) * vv.x
              + tanh_fast(xa0.y + xa1.y + h2f((ushort)(ya >> 16))) * vv.y
              + tanh_fast(xa0.z + xa1.z + h2f((ushort)yb)) * vv.z
              + tanh_fast(xa0.w + xa1.w + h2f((ushort)(yb >> 16))) * vv.w;
        }
        ps += __shfl_xor(ps, 1, 64);
        ps += __shfl_xor(ps, 2, 64);
        ps += __shfl_xor(ps, 4, 64);
        if (lq == 0) l_s[tq] = ps;
      }
      __threadfence_block();
      if ((threadIdx.x & 63) == 0)
        __hip_atomic_fetch_add(&flagL, 1u, __ATOMIC_RELEASE, __HIP_MEMORY_SCOPE_WORKGROUP);

      if (idx < 64) {
        // softmax + beta pack + ytil (wave 8 only)
        const unsigned tgtL = 8u * (unsigned)(t + 1);
        while (__hip_atomic_load(&flagL, __ATOMIC_ACQUIRE, __HIP_MEMORY_SCOPE_WORKGROUP) < tgtL) {}
        float v = l_s[idx];
        float mx = v;
        #pragma unroll
        for (int o = 1; o < 64; o <<= 1) mx = fmaxf(mx, __shfl_xor(mx, o, 64));
        float e = __expf(v - mx);
        float sm = e;
        #pragma unroll
        for (int o = 1; o < 64; o <<= 1) sm += __shfl_xor(sm, o, 64);
        float beta = e / sm;
        float bnext = __shfl_xor(beta, 1, 64);
        if ((idx & 1) == 0) beta2_s[idx >> 1] = pk2(beta, bnext);
        float term = beta * e_s[idx] + ((idx == t) ? (wty * yv_r + bwt) : 0.0f);
        float yt = wave_sum(term);
        if (idx == 0) ytil_s = yt;
      }
    }
    __syncthreads();  // B_end: gates_s + ytil_s (+beta2_s) ready

    // ===== LSTM cell: threads 512..767 =====
    if (tid >= 512 && tid < 768) {
      const int hh = tid - 512;
      const float ytil = ytil_s;
      float fi = sigm(gates_s[hh]       + ytil * wih0);
      float ff = sigm(gates_s[256 + hh] + ytil * wih1);
      float fg = tanh_fast(gates_s[512 + hh] + ytil * wih2);
      float fo = sigm(gates_s[768 + hh] + ytil * wih3);
      float spn = ff * sp_reg + fi * fg;
      float dn  = fo * tanh_fast(spn);
      sp_reg = spn;
      dsp_s[hh]       = dn;
      dsp_s[256 + hh] = spn;
      if (t == Tx - 1) dcfin_s[hh] = dn;
    }
    __syncthreads();  // B_state: d/sp(t) ready
  }

  // ===== one-time context c (beta of t=63): threads >=512, 2 lanes per m ====
  if (tid >= 512) {
    const int idx = tid - 512;
    const int m = idx >> 1, q = idx & 1;
    float acc = 0.0f;
    #pragma unroll 4
    for (int j = 0; j < 32; ++j) {
      const int tt = q * 32 + j;
      uint bp = beta2_s[tt >> 1];
      float bb = (tt & 1) ? h2f((ushort)(bp >> 16)) : h2f((ushort)bp);
      acc += bb * enc[(size_t)tt * BM + (size_t)b * Mx + m];
    }
    acc += __shfl_xor(acc, 1, 64);
    if (q == 0) dcfin_s[256 + m] = acc;
  }
  __syncthreads();

  // ===== Epilogue: out[b] = v_y . (W_y @ [d|c] + b_Wy) + b_vy =====
  {
    float a = 0.0f;
    const float* wy = Wyt + h;
    for (int k = 128 * p; k < 128 * p + 128; ++k)
      a += wy[(size_t)k * 256] * dcfin_s[k];
    gates_s[p * 256 + h] = a;     // gates_s reused as epilogue partials
  }
  __syncthreads();
  if (tid < 256) {
    float aa = gates_s[h] + gates_s[256 + h] + gates_s[512 + h] + gates_s[768 + h]
             + b_Wy[h];
    float po = aa * v_y[h];
    po = wave_sum(po);
    if ((tid & 63) == 0) red_s[tid >> 6] = po;
  }
  __syncthreads();
  if (tid == 0) out[b] = red_s[0] + red_s[1] + red_s[2] + red_s[3] + b_vy[0];
}

extern "C" void kernel_launch(void* const* d_in, const int* in_sizes, int n_in,
                              void* d_out, int out_size, void* d_ws, size_t ws_size,
                              hipStream_t stream) {
  const float* enc     = (const float*)d_in[0];
  const float* yv      = (const float*)d_in[1];
  const float* W_d     = (const float*)d_in[2];
  const float* b_Wd    = (const float*)d_in[3];
  const float* U_d     = (const float*)d_in[4];
  const float* v_d     = (const float*)d_in[5];
  const float* w_tilda = (const float*)d_in[6];
  const float* b_wt    = (const float*)d_in[7];
  const float* W_ih    = (const float*)d_in[8];
  const float* W_hh    = (const float*)d_in[9];
  const float* b_ih    = (const float*)d_in[10];
  const float* b_hh    = (const float*)d_in[11];
  const float* W_y     = (const float*)d_in[12];
  const float* b_Wy    = (const float*)d_in[13];
  const float* v_y     = (const float*)d_in[14];
  const float* b_vy    = (const float*)d_in[15];
  float* outp = (float*)d_out;

  char* ws = (char*)d_ws;
  uint4* Whh8q = (uint4*)ws;                               // 256 KB
  uint4* Wd8q  = (uint4*)(ws + (256 << 10));               // 128 KB
  uint4* Ud8   = (uint4*)(ws + (384 << 10));               // 128 KB
  float* Wyt   = (float*)(ws + (512 << 10));               // 512 KB
  ushort* Y1   = (ushort*)(ws + (1024 << 10));             // 8 MB

  const int DYN_LDS = 128 << 10;   // W_d fp8 slab in dynamic LDS
  hipFuncSetAttribute((const void*)fused,
                      hipFuncAttributeMaxDynamicSharedMemorySize, DYN_LDS);

  hipLaunchKernelGGL(pack_weights, dim3(208), dim3(256), 0, stream,
                     W_d, W_hh, U_d, W_y, Whh8q, Wd8q, Ud8, Wyt);
  hipLaunchKernelGGL(fused, dim3(Bx), dim3(NT), DYN_LDS, stream,
                     enc, yv, b_Wd, v_d, w_tilda, b_wt, W_ih, b_ih, b_hh,
                     b_Wy, v_y, b_vy, Whh8q, Wd8q, Ud8, Wyt, Y1, outp);
}